// Round 17
// baseline (298.654 us; speedup 1.0000x reference)
//
#include <hip/hip_runtime.h>
#include <hip/hip_bf16.h>

// Attention block: QKV GEMM -> 16-head softmax attention -> proj GEMM.
// B=4, T=2048, C=1024, nh=16, hs=64. All GEMMs in bf16 MFMA, fp32 accum.
// Reference "bug": attn out (B,nh,T,hs) flat is reinterpreted as (B*T, C) for the
// projection -> we just feed the flat [bh][t][d] buffer as proj GEMM's A matrix.
//
// GEMM (r14, unchanged): 128x128 tile, BK=64, 2-slot dbuf global_load_lds
// prefetch, pre-swizzled source + XOR read, bijective XCD stripe remap.
// attn (r17 = r16 fixed): QK-ahead pipeline + V in registers. r16's K staging
// violated the global_load_lds wave-uniform-base+lane*16 rule (per-lane 32B
// spacing -> HW scrambled chunks). Fixed: wave w stages chunks [128w,128w+128)
// with dst = base(w) + lane*16B exactly.

typedef __attribute__((ext_vector_type(8)))  short bf16x8;   // MFMA A/B frag
typedef __attribute__((ext_vector_type(4)))  float f32x4;    // 16x16 C/D frag
typedef __attribute__((ext_vector_type(16))) float f32x16;   // 32x32 C/D frag
typedef __attribute__((ext_vector_type(2)))  unsigned u32x2;

typedef __attribute__((address_space(3))) unsigned lds_u32_t;
typedef __attribute__((address_space(1))) unsigned glb_u32_t;

__device__ __forceinline__ void async_cp16(const short* g, short* l) {
    __builtin_amdgcn_global_load_lds((glb_u32_t*)g, (lds_u32_t*)l, 16, 0, 0);
}

__device__ __forceinline__ float exp2fast(float x) {
    return __builtin_amdgcn_exp2f(x);    // v_exp_f32: 2^x
}

__device__ __forceinline__ short f2bf(float f) {
    union { float f; unsigned u; } v; v.f = f;
    unsigned r = v.u + 0x7fffu + ((v.u >> 16) & 1u);   // RNE (inputs are finite)
    return (short)(r >> 16);
}

__device__ __forceinline__ unsigned cvt_pk_bf16(float lo, float hi) {
    unsigned r;
    asm("v_cvt_pk_bf16_f32 %0, %1, %2" : "=v"(r) : "v"(lo), "v"(hi));
    return r;   // bits[15:0]=bf16(lo), bits[31:16]=bf16(hi)
}

// ---------------- fused fp32 -> bf16 conversion (one launch for all 3 inputs) ----
__global__ __launch_bounds__(256) void cvt3_kernel(
    const float4* __restrict__ x,  const float4* __restrict__ ww,
    const float4* __restrict__ pw, short4* __restrict__ xb,
    short4* __restrict__ wwb,      short4* __restrict__ pwb) {
    const int b = blockIdx.x;
    const float4* in; short4* out; int i;
    if (b < 8192)       { in = x;  out = xb;  i = b * 256 + threadIdx.x; }
    else if (b < 11264) { in = ww; out = wwb; i = (b - 8192) * 256 + threadIdx.x; }
    else                { in = pw; out = pwb; i = (b - 11264) * 256 + threadIdx.x; }
    float4 v = in[i];
    short4 o;
    o.x = f2bf(v.x); o.y = f2bf(v.y); o.z = f2bf(v.z); o.w = f2bf(v.w);
    out[i] = o;
}

// ---------------- GEMM: C[m][n] = sum_k A[m][k]*W[n][k] + bias[n] ----------------
// (r14, unchanged — 2-phase ceiling + XCD stripe remap)
template<int EPI>
__global__ __launch_bounds__(256) void gemm_bf16(
    const short* __restrict__ A, const short* __restrict__ W,
    const float* __restrict__ bias, float* __restrict__ outF,
    short* __restrict__ kout, short* __restrict__ qout, short* __restrict__ vtout,
    int M, int N, int K)
{
    __shared__ short lA[2][128 * 64];
    __shared__ short lB[2][128 * 64];
    const int tid  = threadIdx.x;
    const int lane = tid & 63;
    const int wave = tid >> 6;
    const int wM = (wave >> 1) * 64;
    const int wN = (wave & 1) * 64;
    const int l15 = lane & 15, l4 = lane >> 4;
    const int rsw = (lane & 7) << 3;            // read-side XOR (shorts)

    // bijective XCD stripe remap (gridDim.y == 64): lin%8 = XCD = by'/8
    const int lin = blockIdx.y * gridDim.x + blockIdx.x;
    const int byp = 8 * (lin & 7) + ((lin >> 3) & 7);
    const int bxp = lin >> 6;
    const int rowBase = byp * 128;
    const int colBase = bxp * 128;

    auto STAGE = [&](int t, int buf) {
        const int k0 = t * 64;
        #pragma unroll
        for (int i = 0; i < 4; ++i) {
            int idx = i * 256 + tid;
            int r   = idx >> 3;                       // tile row 0..127
            int cp  = ((idx & 7) ^ (r & 7)) * 8;      // pre-swizzled source col
            int eo  = idx * 8;                        // linear LDS offset (shorts)
            async_cp16(A + (size_t)(rowBase + r) * K + k0 + cp, &lA[buf][eo]);
            async_cp16(W + (size_t)(colBase + r) * K + k0 + cp, &lB[buf][eo]);
        }
    };

    f32x4 acc[4][4] = {};
    const int NT = K >> 6;

    STAGE(0, 0);
    __syncthreads();

    int cur = 0;
    for (int t = 0; t < NT; ++t) {
        if (t + 1 < NT) STAGE(t + 1, cur ^ 1);   // prefetch: in flight all phase
        #pragma unroll
        for (int kt = 0; kt < 2; ++kt) {
            bf16x8 af[4], bfr[4];
            #pragma unroll
            for (int mt = 0; mt < 4; ++mt)
                af[mt] = *(const bf16x8*)(
                    &lA[cur][(wM + mt * 16 + l15) * 64 + ((kt * 32 + l4 * 8) ^ rsw)]);
            #pragma unroll
            for (int nt = 0; nt < 4; ++nt)
                bfr[nt] = *(const bf16x8*)(
                    &lB[cur][(wN + nt * 16 + l15) * 64 + ((kt * 32 + l4 * 8) ^ rsw)]);
            #pragma unroll
            for (int mt = 0; mt < 4; ++mt)
                #pragma unroll
                for (int nt = 0; nt < 4; ++nt)
                    acc[mt][nt] = __builtin_amdgcn_mfma_f32_16x16x32_bf16(
                        af[mt], bfr[nt], acc[mt][nt], 0, 0, 0);
        }
        __syncthreads();   // drains prefetch vmcnt + read-done before overwrite
        cur ^= 1;
    }

    #pragma unroll
    for (int mt = 0; mt < 4; ++mt) {
        #pragma unroll
        for (int nt = 0; nt < 4; ++nt) {
            const int n  = colBase + wN + nt * 16 + l15;
            const int mb = rowBase + wM + mt * 16 + l4 * 4;
            const float bv = bias[n];
            #pragma unroll
            for (int r = 0; r < 4; ++r) {
                const int m = mb + r;
                float val = acc[mt][nt][r] + bv;
                if (EPI == 0) {
                    int b = m >> 11, t = m & 2047;
                    int j = n >> 10, hd = n & 1023;
                    int h = hd >> 6, d = hd & 63;
                    size_t base = ((size_t)(b * 16 + h) * 2048 + t) * 64 + d;
                    // fold hs^-0.5 * log2(e) into Q so softmax runs in exp2 domain
                    if (j == 0)      kout[base] = f2bf(val);
                    else if (j == 1) qout[base] = f2bf(val * 0.180336879f);
                    else             vtout[((size_t)(b * 16 + h) * 64 + d) * 2048 + t] = f2bf(val);
                } else {
                    outF[(size_t)m * N + n] = val;
                }
            }
        }
    }
}

// ---------------- flash attention, swapped-QK^T 32x32x16, QK-ahead + V-in-reg ---
// grid: 1024 blocks (XCD-remapped), 256 threads = 4 waves; wave owns 32 q-rows.
// Per iteration: VLOAD(t-1)->regs; STAGE_K(t+1)->LDS; QK(t) MFMAs; softmax+PV
// of t-1; 1 sync/iter. K staging: wave w owns rows [16w,16w+16), dst =
// wave-uniform base + lane*16B (global_load_lds rule), src col swizzled
// 8*((lane&7)^(lane>>3)) — read side XOR (row&7)*8 matches.
__global__ __launch_bounds__(256) void attn_kernel(
    const short* __restrict__ Q, const short* __restrict__ Km,
    const short* __restrict__ Vt, short* __restrict__ O)
{
    __shared__ short kbuf[2][64 * 64];

    const int tid  = threadIdx.x;
    const int lane = tid & 63;
    const int wave = tid >> 6;
    const int l31 = lane & 31;
    const int l1  = lane >> 5;

    // XCD remap: wg%8 picks the XCD -> give all 16 q-blocks of a head one XCD.
    const int b     = blockIdx.x;
    const int xcd   = b & 7;
    const int inner = b >> 3;
    const int bx    = inner & 15;
    const int bh    = xcd * 8 + (inner >> 4);
    const int q0    = bx * 128 + wave * 32;

    const short* Qh = Q  + (size_t)bh * 2048 * 64;
    const short* Kh = Km + (size_t)bh * 2048 * 64;
    const short* Vh = Vt + (size_t)bh * 64 * 2048;

    const int rsw = (l31 & 7) << 3;            // read-side swizzle (shorts)

    // K staging: wave w stages rows 16w..16w+15 (two 8-row groups), dst is
    // wave-uniform base + lane*8 shorts (= lane*16 B, HW requirement).
    const int krow0 = 16 * wave + (lane >> 3);        // rows 16w..16w+7
    const int scol  = 8 * ((lane & 7) ^ (lane >> 3)); // pre-swizzled source col
    const short* ksrc0 = Kh + (size_t)krow0 * 64 + scol;        // group 0
    const short* ksrc1 = ksrc0 + 8 * 64;                        // rows +8
    short* kdst0 = &kbuf[0][wave * 1024 + lane * 8];
    short* kdst1 = kdst0 + 512;
    auto STAGE_K = [&](int buf) {              // advances K src by one tile
        async_cp16(ksrc0, kdst0 + buf * 4096);
        async_cp16(ksrc1, kdst1 + buf * 4096);
        ksrc0 += 64 * 64;
        ksrc1 += 64 * 64;
    };

    // V loads -> registers: per lane two d-rows (l31, 32+l31), 4x16B each.
    const short* vsrc0 = Vh + (size_t)l31 * 2048 + l1 * 8;
    const short* vsrc1 = Vh + (size_t)(32 + l31) * 2048 + l1 * 8;
    bf16x8 vf[4][2];
    auto VLOAD = [&]() {                       // advances V src by one tile
        #pragma unroll
        for (int s = 0; s < 4; ++s) {
            vf[s][0] = *(const bf16x8*)(vsrc0 + s * 16);
            vf[s][1] = *(const bf16x8*)(vsrc1 + s * 16);
        }
        vsrc0 += 64;
        vsrc1 += 64;
    };

    // Q as B-operand: n = q = l31, k = d = s*16 + l1*8 + j
    bf16x8 qf[4];
    #pragma unroll
    for (int s = 0; s < 4; ++s)
        qf[s] = *(const bf16x8*)(Qh + (size_t)(q0 + l31) * 64 + s * 16 + l1 * 8);

    // ones B-frag for the row-sum MFMA
    union { unsigned u[4]; bf16x8 v; } onesu;
    #pragma unroll
    for (int j = 0; j < 4; ++j) onesu.u[j] = 0x3F803F80u;
    const bf16x8 onesf = onesu.v;

    f32x16 o[2] = {};
    f32x16 ol   = {};     // row-sums, same reg mapping as o
    f32x16 s2a[2], s2b[2];

    // QK^T swapped: out[t] = K_tile(half t) x Q -> D[kv][q], q = l31
    auto QK = [&](int kb, f32x16* out) {
        f32x16 r0v = {}, r1v = {};
        __builtin_amdgcn_s_setprio(1);
        #pragma unroll
        for (int s = 0; s < 4; ++s) {
            bf16x8 kf0 = *(const bf16x8*)(
                &kbuf[kb][(l31) * 64 + ((s * 16 + l1 * 8) ^ rsw)]);
            r0v = __builtin_amdgcn_mfma_f32_32x32x16_bf16(kf0, qf[s], r0v, 0, 0, 0);
            bf16x8 kf1 = *(const bf16x8*)(
                &kbuf[kb][(32 + l31) * 64 + ((s * 16 + l1 * 8) ^ rsw)]);
            r1v = __builtin_amdgcn_mfma_f32_32x32x16_bf16(kf1, qf[s], r1v, 0, 0, 0);
        }
        __builtin_amdgcn_s_setprio(0);
        out[0] = r0v; out[1] = r1v;
    };

    // softmax (no-max exp2) + pack + PV (V from regs)
    auto SMPV = [&](f32x16* s2) {
        #pragma unroll
        for (int t = 0; t < 2; ++t)
            #pragma unroll
            for (int i = 0; i < 16; ++i)
                s2[t][i] = exp2fast(s2[t][i]);
        bf16x8 pa[4];
        #pragma unroll
        for (int t = 0; t < 2; ++t) {
            #pragma unroll
            for (int sl = 0; sl < 2; ++sl) {
                unsigned A0 = cvt_pk_bf16(s2[t][8 * sl + 0], s2[t][8 * sl + 1]);
                unsigned A1 = cvt_pk_bf16(s2[t][8 * sl + 2], s2[t][8 * sl + 3]);
                unsigned B0 = cvt_pk_bf16(s2[t][8 * sl + 4], s2[t][8 * sl + 5]);
                unsigned B1 = cvt_pk_bf16(s2[t][8 * sl + 6], s2[t][8 * sl + 7]);
                u32x2 ra = __builtin_amdgcn_permlane32_swap(A0, B0, false, false);
                u32x2 rb = __builtin_amdgcn_permlane32_swap(A1, B1, false, false);
                union { unsigned u[4]; bf16x8 v; } w;
                w.u[0] = ra.x;
                w.u[1] = rb.x;
                w.u[2] = ra.y;
                w.u[3] = rb.y;
                pa[2 * t + sl] = w.v;
            }
        }
        __builtin_amdgcn_s_setprio(1);
        #pragma unroll
        for (int s = 0; s < 4; ++s) {
            #pragma unroll
            for (int dt = 0; dt < 2; ++dt)
                o[dt] = __builtin_amdgcn_mfma_f32_32x32x16_bf16(pa[s], vf[s][dt], o[dt], 0, 0, 0);
            ol = __builtin_amdgcn_mfma_f32_32x32x16_bf16(pa[s], onesf, ol, 0, 0, 0);
        }
        __builtin_amdgcn_s_setprio(0);
    };

    // ---- prologue: K(0) -> kbuf[0]
    STAGE_K(0);
    __syncthreads();
    // ---- tile 0: stage K(1); QK(0); (no previous tile)
    STAGE_K(1);
    QK(0, s2a);
    __syncthreads();
    // ---- tiles 1..30 in odd/even pairs (15 bodies)
    for (int i = 0; i < 15; ++i) {
        // odd tile 2i+1: V(2i)->regs; K(2i+2)->kb0; QK->s2b; SMPV(tile 2i)
        VLOAD();
        STAGE_K(0);
        QK(1, s2b);
        SMPV(s2a);
        __syncthreads();
        // even tile 2i+2: V(2i+1)->regs; K(2i+3)->kb1; QK->s2a; SMPV(2i+1)
        VLOAD();
        STAGE_K(1);
        QK(0, s2a);
        SMPV(s2b);
        __syncthreads();
    }
    // ---- tile 31: V(30); QK(31)->s2b; SMPV(tile 30)
    VLOAD();
    QK(1, s2b);
    SMPV(s2a);
    // ---- drain: V(31); SMPV(tile 31)   (regs only, no barrier needed)
    VLOAD();
    SMPV(s2b);

    // ---- epilogue: normalize by lane-local 1/ol[r] (same reg mapping as o)
    #pragma unroll
    for (int g = 0; g < 4; ++g)
        #pragma unroll
        for (int rr = 0; rr < 4; ++rr) {
            float invl = 1.f / ol[g * 4 + rr];
            int qrow = q0 + rr + 8 * g + 4 * l1;
            size_t base = ((size_t)bh * 2048 + qrow) * 64 + l31;
            O[base]      = f2bf(o[0][g * 4 + rr] * invl);
            O[base + 32] = f2bf(o[1][g * 4 + rr] * invl);
        }
}

// ---------------- launcher ----------------
extern "C" void kernel_launch(void* const* d_in, const int* in_sizes, int n_in,
                              void* d_out, int out_size, void* d_ws, size_t ws_size,
                              hipStream_t stream) {
    const float* x  = (const float*)d_in[0];   // (4,2048,1024)
    const float* ww = (const float*)d_in[1];   // (3072,1024)
    const float* wb = (const float*)d_in[2];   // (3072,)
    const float* pwt = (const float*)d_in[3];  // (1024,1024)
    const float* pb  = (const float*)d_in[4];  // (1024,)
    float* out = (float*)d_out;                // (4,2048,1024) fp32

    short* ws  = (short*)d_ws;
    short* xb  = ws;                      // 8192*1024
    short* wwb = xb  + 8192 * 1024;       // 3072*1024
    short* pwb = wwb + 3072 * 1024;       // 1024*1024
    short* qb  = pwb + 1024 * 1024;       // 64*2048*64  [bh][t][d] (pre-scaled)
    short* kb  = qb  + 64 * 2048 * 64;    // 64*2048*64  [bh][t][d]
    short* vtb = kb  + 64 * 2048 * 64;    // 64*64*2048  [bh][d][t]
    short* ob  = vtb + 64 * 2048 * 64;    // 64*2048*64  flat = proj A matrix

    cvt3_kernel<<<12288, 256, 0, stream>>>(
        (const float4*)x, (const float4*)ww, (const float4*)pwt,
        (short4*)xb, (short4*)wwb, (short4*)pwb);

    gemm_bf16<0><<<dim3(24, 64), 256, 0, stream>>>(
        xb, wwb, wb, nullptr, kb, qb, vtb, 8192, 3072, 1024);

    attn_kernel<<<1024, 256, 0, stream>>>(qb, kb, vtb, ob);

    gemm_bf16<1><<<dim3(8, 64), 256, 0, stream>>>(
        ob, pwb, pb, out, nullptr, nullptr, nullptr, 8192, 1024, 1024);
}

// Round 18
// 198.197 us; speedup vs baseline: 1.5069x; 1.5069x over previous
//
#include <hip/hip_runtime.h>
#include <hip/hip_bf16.h>

// Attention block: QKV GEMM -> 16-head softmax attention -> proj GEMM.
// B=4, T=2048, C=1024, nh=16, hs=64. All GEMMs in bf16 MFMA, fp32 accum.
// Reference "bug": attn out (B,nh,T,hs) flat is reinterpreted as (B*T, C) for the
// projection -> we just feed the flat [bh][t][d] buffer as proj GEMM's A matrix.
//
// GEMM (r14): 128x128 tile, BK=64, 2-slot dbuf global_load_lds prefetch,
// pre-swizzled source + XOR read, bijective XCD stripe remap.
// attn (r15, reverted from failed r16/r17 V-in-reg: +44 VGPR -> occupancy cliff):
// QK-ahead pipeline — QK^T(t+1) MFMAs issue BEFORE softmax(t) VALU; K,V in LDS
// dbuf; no-max exp2 softmax; T12 repack; ones-MFMA row-sum; XCD remap.

typedef __attribute__((ext_vector_type(8)))  short bf16x8;   // MFMA A/B frag
typedef __attribute__((ext_vector_type(4)))  float f32x4;    // 16x16 C/D frag
typedef __attribute__((ext_vector_type(16))) float f32x16;   // 32x32 C/D frag
typedef __attribute__((ext_vector_type(2)))  unsigned u32x2;

typedef __attribute__((address_space(3))) unsigned lds_u32_t;
typedef __attribute__((address_space(1))) unsigned glb_u32_t;

__device__ __forceinline__ void async_cp16(const short* g, short* l) {
    __builtin_amdgcn_global_load_lds((glb_u32_t*)g, (lds_u32_t*)l, 16, 0, 0);
}

__device__ __forceinline__ float exp2fast(float x) {
    return __builtin_amdgcn_exp2f(x);    // v_exp_f32: 2^x
}

__device__ __forceinline__ short f2bf(float f) {
    union { float f; unsigned u; } v; v.f = f;
    unsigned r = v.u + 0x7fffu + ((v.u >> 16) & 1u);   // RNE (inputs are finite)
    return (short)(r >> 16);
}

__device__ __forceinline__ unsigned cvt_pk_bf16(float lo, float hi) {
    unsigned r;
    asm("v_cvt_pk_bf16_f32 %0, %1, %2" : "=v"(r) : "v"(lo), "v"(hi));
    return r;   // bits[15:0]=bf16(lo), bits[31:16]=bf16(hi)
}

// ---------------- fused fp32 -> bf16 conversion (one launch for all 3 inputs) ----
__global__ __launch_bounds__(256) void cvt3_kernel(
    const float4* __restrict__ x,  const float4* __restrict__ ww,
    const float4* __restrict__ pw, short4* __restrict__ xb,
    short4* __restrict__ wwb,      short4* __restrict__ pwb) {
    const int b = blockIdx.x;
    const float4* in; short4* out; int i;
    if (b < 8192)       { in = x;  out = xb;  i = b * 256 + threadIdx.x; }
    else if (b < 11264) { in = ww; out = wwb; i = (b - 8192) * 256 + threadIdx.x; }
    else                { in = pw; out = pwb; i = (b - 11264) * 256 + threadIdx.x; }
    float4 v = in[i];
    short4 o;
    o.x = f2bf(v.x); o.y = f2bf(v.y); o.z = f2bf(v.z); o.w = f2bf(v.w);
    out[i] = o;
}

// ---------------- GEMM: C[m][n] = sum_k A[m][k]*W[n][k] + bias[n] ----------------
// (r14, unchanged — 2-phase ceiling + XCD stripe remap)
template<int EPI>
__global__ __launch_bounds__(256) void gemm_bf16(
    const short* __restrict__ A, const short* __restrict__ W,
    const float* __restrict__ bias, float* __restrict__ outF,
    short* __restrict__ kout, short* __restrict__ qout, short* __restrict__ vtout,
    int M, int N, int K)
{
    __shared__ short lA[2][128 * 64];
    __shared__ short lB[2][128 * 64];
    const int tid  = threadIdx.x;
    const int lane = tid & 63;
    const int wave = tid >> 6;
    const int wM = (wave >> 1) * 64;
    const int wN = (wave & 1) * 64;
    const int l15 = lane & 15, l4 = lane >> 4;
    const int rsw = (lane & 7) << 3;            // read-side XOR (shorts)

    // bijective XCD stripe remap (gridDim.y == 64): lin%8 = XCD = by'/8
    const int lin = blockIdx.y * gridDim.x + blockIdx.x;
    const int byp = 8 * (lin & 7) + ((lin >> 3) & 7);
    const int bxp = lin >> 6;
    const int rowBase = byp * 128;
    const int colBase = bxp * 128;

    auto STAGE = [&](int t, int buf) {
        const int k0 = t * 64;
        #pragma unroll
        for (int i = 0; i < 4; ++i) {
            int idx = i * 256 + tid;
            int r   = idx >> 3;                       // tile row 0..127
            int cp  = ((idx & 7) ^ (r & 7)) * 8;      // pre-swizzled source col
            int eo  = idx * 8;                        // linear LDS offset (shorts)
            async_cp16(A + (size_t)(rowBase + r) * K + k0 + cp, &lA[buf][eo]);
            async_cp16(W + (size_t)(colBase + r) * K + k0 + cp, &lB[buf][eo]);
        }
    };

    f32x4 acc[4][4] = {};
    const int NT = K >> 6;

    STAGE(0, 0);
    __syncthreads();

    int cur = 0;
    for (int t = 0; t < NT; ++t) {
        if (t + 1 < NT) STAGE(t + 1, cur ^ 1);   // prefetch: in flight all phase
        #pragma unroll
        for (int kt = 0; kt < 2; ++kt) {
            bf16x8 af[4], bfr[4];
            #pragma unroll
            for (int mt = 0; mt < 4; ++mt)
                af[mt] = *(const bf16x8*)(
                    &lA[cur][(wM + mt * 16 + l15) * 64 + ((kt * 32 + l4 * 8) ^ rsw)]);
            #pragma unroll
            for (int nt = 0; nt < 4; ++nt)
                bfr[nt] = *(const bf16x8*)(
                    &lB[cur][(wN + nt * 16 + l15) * 64 + ((kt * 32 + l4 * 8) ^ rsw)]);
            #pragma unroll
            for (int mt = 0; mt < 4; ++mt)
                #pragma unroll
                for (int nt = 0; nt < 4; ++nt)
                    acc[mt][nt] = __builtin_amdgcn_mfma_f32_16x16x32_bf16(
                        af[mt], bfr[nt], acc[mt][nt], 0, 0, 0);
        }
        __syncthreads();   // drains prefetch vmcnt + read-done before overwrite
        cur ^= 1;
    }

    #pragma unroll
    for (int mt = 0; mt < 4; ++mt) {
        #pragma unroll
        for (int nt = 0; nt < 4; ++nt) {
            const int n  = colBase + wN + nt * 16 + l15;
            const int mb = rowBase + wM + mt * 16 + l4 * 4;
            const float bv = bias[n];
            #pragma unroll
            for (int r = 0; r < 4; ++r) {
                const int m = mb + r;
                float val = acc[mt][nt][r] + bv;
                if (EPI == 0) {
                    int b = m >> 11, t = m & 2047;
                    int j = n >> 10, hd = n & 1023;
                    int h = hd >> 6, d = hd & 63;
                    size_t base = ((size_t)(b * 16 + h) * 2048 + t) * 64 + d;
                    // fold hs^-0.5 * log2(e) into Q so softmax runs in exp2 domain
                    if (j == 0)      kout[base] = f2bf(val);
                    else if (j == 1) qout[base] = f2bf(val * 0.180336879f);
                    else             vtout[((size_t)(b * 16 + h) * 64 + d) * 2048 + t] = f2bf(val);
                } else {
                    outF[(size_t)m * N + n] = val;
                }
            }
        }
    }
}

// ---------------- flash attention, swapped-QK^T 32x32x16, QK-ahead pipeline -----
// grid: 1024 blocks (XCD-remapped), 256 threads = 4 waves; wave owns 32 q-rows.
// Per tile t (1 sync/tile): stage K(t+1),V(t); issue QK(t) MFMAs; THEN run
// softmax+PV of tile t-1 (VALU overlaps the in-flight QK MFMAs); sync.
// Hazards: K(t) staged @t-1 (sync-sep); V(t) read @t+1 (sync-sep), overwritten
// @t+2 (sync-sep). s2a/s2b named per odd/even tile (static reg indexing).
__global__ __launch_bounds__(256) void attn_kernel(
    const short* __restrict__ Q, const short* __restrict__ Km,
    const short* __restrict__ Vt, short* __restrict__ O)
{
    __shared__ short kbuf[2][64 * 64];
    __shared__ short vbuf[2][64 * 64];

    const int tid  = threadIdx.x;
    const int lane = tid & 63;
    const int wave = tid >> 6;
    const int l31 = lane & 31;
    const int l1  = lane >> 5;

    // XCD remap: wg%8 picks the XCD -> give all 16 q-blocks of a head one XCD.
    const int b     = blockIdx.x;
    const int xcd   = b & 7;
    const int inner = b >> 3;
    const int bx    = inner & 15;
    const int bh    = xcd * 8 + (inner >> 4);
    const int q0    = bx * 128 + wave * 32;

    const short* Qh = Q  + (size_t)bh * 2048 * 64;
    const short* Kh = Km + (size_t)bh * 2048 * 64;
    const short* Vh = Vt + (size_t)bh * 64 * 2048;

    const int i8 = lane >> 3, i7 = lane & 7;
    const int srcCol = 8 * (i7 ^ i8);          // pre-swizzled source column (elems)
    const int rsw    = (l31 & 7) << 3;         // read-side swizzle (shorts)

    // Staging: waves 0-1 stage K, waves 2-3 stage V; strength-reduced pointers.
    const short* src[4];
    short* dst0[4];
    int step;
    if (wave < 2) {
        #pragma unroll
        for (int c = 0; c < 4; ++c) {
            int j = wave * 4 + c;
            src[c]  = Kh + (size_t)(8 * j + i8) * 64 + srcCol;
            dst0[c] = &kbuf[0][j * 512 + lane * 8];
        }
        step = 64 * 64;
    } else {
        #pragma unroll
        for (int c = 0; c < 4; ++c) {
            int j = (wave - 2) * 4 + c;
            src[c]  = Vh + (size_t)(8 * j + i8) * 2048 + srcCol;
            dst0[c] = &vbuf[0][j * 512 + lane * 8];
        }
        step = 64;
    }
    auto STAGE_K = [&](int buf) {        // advances K src by one tile per call
        if (wave < 2) {
            #pragma unroll
            for (int c = 0; c < 4; ++c) {
                async_cp16(src[c], dst0[c] + buf * 4096);
                src[c] += step;
            }
        }
    };
    auto STAGE_V = [&](int buf) {        // advances V src by one tile per call
        if (wave >= 2) {
            #pragma unroll
            for (int c = 0; c < 4; ++c) {
                async_cp16(src[c], dst0[c] + buf * 4096);
                src[c] += step;
            }
        }
    };

    // Q as B-operand: n = q = l31, k = d = s*16 + l1*8 + j
    bf16x8 qf[4];
    #pragma unroll
    for (int s = 0; s < 4; ++s)
        qf[s] = *(const bf16x8*)(Qh + (size_t)(q0 + l31) * 64 + s * 16 + l1 * 8);

    // ones B-frag for the row-sum MFMA
    union { unsigned u[4]; bf16x8 v; } onesu;
    #pragma unroll
    for (int j = 0; j < 4; ++j) onesu.u[j] = 0x3F803F80u;
    const bf16x8 onesf = onesu.v;

    f32x16 o[2] = {};
    f32x16 ol   = {};     // row-sums, same reg mapping as o
    f32x16 s2a[2], s2b[2];

    // QK^T swapped: out[t] = K_tile(t-half) x Q -> D[kv][q], q = l31
    auto QK = [&](int kb, f32x16* out) {
        f32x16 r0 = {}, r1 = {};
        __builtin_amdgcn_s_setprio(1);
        #pragma unroll
        for (int s = 0; s < 4; ++s) {
            bf16x8 kf0 = *(const bf16x8*)(
                &kbuf[kb][(l31) * 64 + ((s * 16 + l1 * 8) ^ rsw)]);
            r0 = __builtin_amdgcn_mfma_f32_32x32x16_bf16(kf0, qf[s], r0, 0, 0, 0);
            bf16x8 kf1 = *(const bf16x8*)(
                &kbuf[kb][(32 + l31) * 64 + ((s * 16 + l1 * 8) ^ rsw)]);
            r1 = __builtin_amdgcn_mfma_f32_32x32x16_bf16(kf1, qf[s], r1, 0, 0, 0);
        }
        __builtin_amdgcn_s_setprio(0);
        out[0] = r0; out[1] = r1;
    };

    // softmax (no-max exp2) + pack + PV for a finished score set
    auto SMPV = [&](f32x16* s2, int vb) {
        #pragma unroll
        for (int t = 0; t < 2; ++t)
            #pragma unroll
            for (int i = 0; i < 16; ++i)
                s2[t][i] = exp2fast(s2[t][i]);
        bf16x8 pa[4];
        #pragma unroll
        for (int t = 0; t < 2; ++t) {
            #pragma unroll
            for (int sl = 0; sl < 2; ++sl) {
                unsigned A0 = cvt_pk_bf16(s2[t][8 * sl + 0], s2[t][8 * sl + 1]);
                unsigned A1 = cvt_pk_bf16(s2[t][8 * sl + 2], s2[t][8 * sl + 3]);
                unsigned B0 = cvt_pk_bf16(s2[t][8 * sl + 4], s2[t][8 * sl + 5]);
                unsigned B1 = cvt_pk_bf16(s2[t][8 * sl + 6], s2[t][8 * sl + 7]);
                u32x2 ra = __builtin_amdgcn_permlane32_swap(A0, B0, false, false);
                u32x2 rb = __builtin_amdgcn_permlane32_swap(A1, B1, false, false);
                union { unsigned u[4]; bf16x8 v; } w;
                w.u[0] = ra.x;
                w.u[1] = rb.x;
                w.u[2] = ra.y;
                w.u[3] = rb.y;
                pa[2 * t + sl] = w.v;
            }
        }
        __builtin_amdgcn_s_setprio(1);
        #pragma unroll
        for (int s = 0; s < 4; ++s) {
            #pragma unroll
            for (int dt = 0; dt < 2; ++dt) {
                bf16x8 vf = *(const bf16x8*)(
                    &vbuf[vb][(dt * 32 + l31) * 64 + ((s * 16 + l1 * 8) ^ rsw)]);
                o[dt] = __builtin_amdgcn_mfma_f32_32x32x16_bf16(pa[s], vf, o[dt], 0, 0, 0);
            }
            ol = __builtin_amdgcn_mfma_f32_32x32x16_bf16(pa[s], onesf, ol, 0, 0, 0);
        }
        __builtin_amdgcn_s_setprio(0);
    };

    // ---- prologue: K(0) -> kbuf[0]
    STAGE_K(0);
    __syncthreads();
    // ---- tile 0: stage K(1),V(0); QK(0); (no previous tile)
    STAGE_K(1);
    STAGE_V(0);
    QK(0, s2a);
    __syncthreads();
    // ---- tiles 1..30 in odd/even pairs (15 bodies)
    for (int i = 0; i < 15; ++i) {
        // odd tile t=2i+1: stage K(2i+2)->kb0, V(2i+1)->vb1; QK->s2b; SMPV(tile 2i)
        STAGE_K(0);
        STAGE_V(1);
        QK(1, s2b);
        SMPV(s2a, 0);
        __syncthreads();
        // even tile t=2i+2: stage K(2i+3)->kb1, V(2i+2)->vb0; QK->s2a; SMPV(2i+1)
        STAGE_K(1);
        STAGE_V(0);
        QK(0, s2a);
        SMPV(s2b, 1);
        __syncthreads();
    }
    // ---- tile 31 (odd): no K stage; V(31)->vb1; QK(31)->s2b; SMPV(tile 30)
    STAGE_V(1);
    QK(1, s2b);
    SMPV(s2a, 0);
    __syncthreads();
    // ---- drain: tile 31
    SMPV(s2b, 1);

    // ---- epilogue: normalize by lane-local 1/ol[r] (same reg mapping as o)
    #pragma unroll
    for (int g = 0; g < 4; ++g)
        #pragma unroll
        for (int rr = 0; rr < 4; ++rr) {
            float invl = 1.f / ol[g * 4 + rr];
            int qrow = q0 + rr + 8 * g + 4 * l1;
            size_t base = ((size_t)bh * 2048 + qrow) * 64 + l31;
            O[base]      = f2bf(o[0][g * 4 + rr] * invl);
            O[base + 32] = f2bf(o[1][g * 4 + rr] * invl);
        }
}

// ---------------- launcher ----------------
extern "C" void kernel_launch(void* const* d_in, const int* in_sizes, int n_in,
                              void* d_out, int out_size, void* d_ws, size_t ws_size,
                              hipStream_t stream) {
    const float* x  = (const float*)d_in[0];   // (4,2048,1024)
    const float* ww = (const float*)d_in[1];   // (3072,1024)
    const float* wb = (const float*)d_in[2];   // (3072,)
    const float* pwt = (const float*)d_in[3];  // (1024,1024)
    const float* pb  = (const float*)d_in[4];  // (1024,)
    float* out = (float*)d_out;                // (4,2048,1024) fp32

    short* ws  = (short*)d_ws;
    short* xb  = ws;                      // 8192*1024
    short* wwb = xb  + 8192 * 1024;       // 3072*1024
    short* pwb = wwb + 3072 * 1024;       // 1024*1024
    short* qb  = pwb + 1024 * 1024;       // 64*2048*64  [bh][t][d] (pre-scaled)
    short* kb  = qb  + 64 * 2048 * 64;    // 64*2048*64  [bh][t][d]
    short* vtb = kb  + 64 * 2048 * 64;    // 64*64*2048  [bh][d][t]
    short* ob  = vtb + 64 * 2048 * 64;    // 64*2048*64  flat = proj A matrix

    cvt3_kernel<<<12288, 256, 0, stream>>>(
        (const float4*)x, (const float4*)ww, (const float4*)pwt,
        (short4*)xb, (short4*)wwb, (short4*)pwb);

    gemm_bf16<0><<<dim3(24, 64), 256, 0, stream>>>(
        xb, wwb, wb, nullptr, kb, qb, vtb, 8192, 3072, 1024);

    attn_kernel<<<1024, 256, 0, stream>>>(qb, kb, vtb, ob);

    gemm_bf16<1><<<dim3(8, 64), 256, 0, stream>>>(
        ob, pwb, pb, out, nullptr, nullptr, nullptr, 8192, 1024, 1024);
}